// Round 16
// baseline (219.392 us; speedup 1.0000x reference)
//
#include <hip/hip_runtime.h>
#include <math.h>

#define NN   4096
#define NN4  (NN/4)
#define CAP  128      // slots per row; Poisson(64) -> never hit
#define RPB  2        // rows per block (R16: was 4; smaller blocks -> 8/CU)
#define D3B  (NN/RPB) // 2048 blocks = 8/CU x 256 CU -> fully resident, 32 waves/CU
#define NGRP (D3B/64) // 32 tail groups of 64 blocks
#define GPAD 32       // ints per counter line (128 B)
#define CPAD 32       // ints per scatter counter line (R14: private line/counter)
#define PREP 8        // probe repetition factor (amplify past the 40us fill floor)

// counter indices (ints from ctr base) -- tail cascade only
#define C_TGRP  0                  // 32 lines
#define C_TGLOB (32 * GPAD)

// ---- workspace layout (bytes from d_ws) ----
// ctr  @ 0       : 33*GPAD i32 (4.2 KB) tail cascade counters
// cnt  @ 4608    : NN*CPAD i32 (512 KB) one counter per 128 B line
// entp @ 528896  : NN*CAP u16 (1 MiB)   packed col<<4|w entries (ZEROED)
// ND   @ 1577472 : NN u64 (32 KB)       packed float2 {N, D3}
// ND2  @ 1610240 : NN u64 (32 KB)       probe scratch
// gsum @ 1643008 : NGRP*4 f64 (1 KB)
#define OFF_CNT  4608
#define OFF_ENTP 528896
#define OFF_ND   1577472
#define OFF_ND2  1610240
#define OFF_GSUM 1643008
#define ZBYTES   OFF_ND            // zero ctr+cnt+entp
#define Z4       (ZBYTES / 16)

// ---------------- bootstrap: zero ctr + cnt + entp ----------------
// Zero-filled entp is load-bearing (R10): empty slots decode to (col 0, w 0)
// -> contribute exactly 0 -> no masking anywhere downstream.
__global__ __launch_bounds__(256) void zeroall_kernel(float4* __restrict__ z) {
    int t = blockIdx.x * 256 + threadIdx.x;
    if (t < Z4) z[t] = make_float4(0.f, 0.f, 0.f, 0.f);
}

// ---------------- scatter: cached 2 B stores (R15 cached + R16 16-bit) -------
// A = scatter + A^T - diag(diag): row s gets (d,w), row d gets (s,w) once.
// Entry = col<<4 | min(w,15): tri_w are exact small ints (ones); duplicates
// stay raw (w=1 each), merged later in LDS. Whole table 1 MiB -> L2-resident.
__global__ void scatter_kernel(const int* __restrict__ idx,
                               const float* __restrict__ wgt,
                               int* __restrict__ cnt,
                               unsigned short* __restrict__ entp, int m) {
    int e = blockIdx.x * blockDim.x + threadIdx.x;
    if (e < m) {
        int2 sd = ((const int2*)idx)[e];
        int s = sd.x, d = sd.y;
        unsigned ival = (unsigned)(int)wgt[e];
        if (ival > 15u) ival = 15u;
        int p = atomicAdd(cnt + s * CPAD, 1);     // device RMW, private line
        if (p < CAP) entp[(size_t)s * CAP + p] = (unsigned short)(((unsigned)d << 4) | ival);
        if (s != d) {
            int q = atomicAdd(cnt + d * CPAD, 1);
            if (q < CAP) entp[(size_t)d * CAP + q] = (unsigned short)(((unsigned)s << 4) | ival);
        }
    }
}

// ---------------- P2 core: diag(A^3) + rowsum for RPB rows ------------------
// diag(A^3)_i = sum_{(j,w) in row i} w * sum_{(k,w') in row j} w' * A_ik;
// A_ik from dense LDS image (LDS atomicAdd merge; exact small-int f32 adds ->
// order-independent -> deterministic). One dword/lane = one whole 128-slot
// neighbor row (16-bit entries); 4 items in flight per wave.
__device__ __forceinline__ void p2_pass(
        const int* __restrict__ cnt, const unsigned* __restrict__ entp32,
        unsigned long long* __restrict__ NDout,
        int i0, int tid, int warp, int lane,
        float* lrow, int* lcol, float* lval, float* red, bool doinner) {
    float4* l4 = (float4*)lrow;
    for (int rr = 0; rr < RPB; ++rr) {
        const int i = i0 + rr;
        int mi = cnt[i * CPAD];
        if (mi > CAP) mi = CAP;
        for (int k = tid; k < NN4; k += 256) l4[k] = make_float4(0.f, 0.f, 0.f, 0.f);
        __syncthreads();

        float nsum = 0.f;
        if (tid < 64) {                       // 64 dwords = all 128 slots
            unsigned q = entp32[(size_t)i * 64 + tid];
            unsigned e0 = q & 0xffffu, e1 = q >> 16;
            int c0 = (int)(e0 >> 4), c1 = (int)(e1 >> 4);
            float w0 = (float)(e0 & 15u), w1 = (float)(e1 & 15u);
            lcol[2 * tid]     = c0; lval[2 * tid]     = w0;
            lcol[2 * tid + 1] = c1; lval[2 * tid + 1] = w1;
            atomicAdd(&lrow[c0], w0);         // merge dups; empty slots add 0 to lrow[0]
            atomicAdd(&lrow[c1], w1);
            nsum = w0 + w1;
        }
        if (warp == 0) {
            for (int o = 32; o; o >>= 1) nsum += __shfl_down(nsum, o);
            if (lane == 0) red[0] = nsum;
        }
        __syncthreads();

        float acc = 0.f;
        if (doinner) {
            for (int t = warp; t < mi; t += 16) {
                const int t1 = t + 4, t2 = t + 8, t3 = t + 12;
                const bool b1 = t1 < mi, b2 = t2 < mi, b3 = t3 < mi;
                int   c0 = lcol[t];
                int   c1 = b1 ? lcol[t1] : 0;
                int   c2 = b2 ? lcol[t2] : 0;
                int   c3 = b3 ? lcol[t3] : 0;
                float a0 = lval[t];
                float a1 = b1 ? lval[t1] : 0.f;
                float a2 = b2 ? lval[t2] : 0.f;
                float a3 = b3 ? lval[t3] : 0.f;
                unsigned q0 = entp32[(size_t)c0 * 64 + lane];  // 4 indep 256 B loads
                unsigned q1 = entp32[(size_t)c1 * 64 + lane];
                unsigned q2 = entp32[(size_t)c2 * 64 + lane];
                unsigned q3 = entp32[(size_t)c3 * 64 + lane];
                float d0 = (float)(q0 & 15u) * lrow[(q0 >> 4) & 4095u]
                         + (float)((q0 >> 16) & 15u) * lrow[q0 >> 20];
                float d1 = (float)(q1 & 15u) * lrow[(q1 >> 4) & 4095u]
                         + (float)((q1 >> 16) & 15u) * lrow[q1 >> 20];
                float d2 = (float)(q2 & 15u) * lrow[(q2 >> 4) & 4095u]
                         + (float)((q2 >> 16) & 15u) * lrow[q2 >> 20];
                float d3 = (float)(q3 & 15u) * lrow[(q3 >> 4) & 4095u]
                         + (float)((q3 >> 16) & 15u) * lrow[q3 >> 20];
                acc += a0 * d0 + a1 * d1 + a2 * d2 + a3 * d3;
            }
        }
        for (int o = 32; o; o >>= 1) acc += __shfl_down(acc, o);
        if (lane == 0) red[4 + warp] = acc;
        __syncthreads();

        if (tid == 0) {
            float2 nd = make_float2(red[0], red[4] + red[5] + red[6] + red[7]);
            unsigned long long bits;
            __builtin_memcpy(&bits, &nd, 8);
            __hip_atomic_store(NDout + i, bits, __ATOMIC_RELAXED, __HIP_MEMORY_SCOPE_AGENT);
        }
        __syncthreads();   // lrow/red reuse across rows
    }
}

// ---------------- probe: amplified P2, no tail (diagnostic) -----------------
// doinner=1: full pass x PREP. doinner=0: everything but the inner loop.
// Writes scratch ND2 (never read). Runtime flag -> no DCE, uniform branch.
__global__ __launch_bounds__(256, 8) void probe_kernel(
        const int* __restrict__ cnt, const unsigned* __restrict__ entp32,
        unsigned long long* __restrict__ ND2, int doinner) {
    __shared__ float lrow[NN];
    __shared__ int   lcol[CAP];
    __shared__ float lval[CAP];
    __shared__ float red[8];
    const int tid = threadIdx.x, warp = tid >> 6, lane = tid & 63;
    for (int rep = 0; rep < PREP; ++rep)
        p2_pass(cnt, entp32, ND2, blockIdx.x * RPB, tid, warp, lane,
                lrow, lcol, lval, red, doinner != 0);
}

// ---------------- real: P2 + cascade OLS/residual tail ----------------------
__global__ __launch_bounds__(256, 8) void diag3stats_kernel(
        const int* __restrict__ cnt, const unsigned* __restrict__ entp32,
        unsigned long long* __restrict__ ND,
        const int* __restrict__ lst, int nl,
        int* __restrict__ ctr, double* __restrict__ gsum,
        float* __restrict__ out) {
    __shared__ float  lrow[NN];
    __shared__ int    lcol[CAP];
    __shared__ float  lval[CAP];
    __shared__ float  red[8];
    __shared__ int    flag;
    __shared__ double dsum[4][4];
    __shared__ double wb[2];
    __shared__ double sh[4];

    const int tid = threadIdx.x, bid = blockIdx.x;
    const int warp = tid >> 6, lane = tid & 63;

    p2_pass(cnt, entp32, ND, bid * RPB, tid, warp, lane,
            lrow, lcol, lval, red, true);

    // ---- cascade tail (non-blocking; only finishers continue) --------------
    if (tid == 0) {
        asm volatile("s_waitcnt vmcnt(0)" ::: "memory");  // drain ND stores
        int v = __hip_atomic_fetch_add(ctr + C_TGRP + (bid >> 6) * GPAD, 1,
                                       __ATOMIC_RELAXED, __HIP_MEMORY_SCOPE_AGENT);
        flag = (v == 63);
    }
    __syncthreads();
    if (!flag) return;

    // group finisher: 64 blocks x 2 rows = 128 rows -> fp64 OLS partials
    const int g = bid >> 6;
    {
        double p1 = 0, p2 = 0, p3 = 0, p4 = 0;
        if (tid < 128) {
            unsigned long long bits = __hip_atomic_load(ND + (g * 128 + tid),
                                                        __ATOMIC_RELAXED, __HIP_MEMORY_SCOPE_AGENT);
            float2 nd; __builtin_memcpy(&nd, &bits, 8);
            double Nd = (double)nd.x;
            double Ed = Nd + 0.5 * (double)nd.y;
            double ln = (double)logf((float)(Nd + 1e-20));
            double le = (double)logf((float)(Ed + 1e-20));
            p1 = ln; p2 = ln * ln; p3 = le; p4 = ln * le;
        }
        for (int o = 32; o; o >>= 1) {
            p1 += __shfl_down(p1, o);
            p2 += __shfl_down(p2, o);
            p3 += __shfl_down(p3, o);
            p4 += __shfl_down(p4, o);
        }
        if (lane == 0) {
            dsum[warp][0] = p1; dsum[warp][1] = p2;
            dsum[warp][2] = p3; dsum[warp][3] = p4;
        }
        __syncthreads();
        if (tid == 0) {
            for (int k = 0; k < 4; ++k) {
                double v = dsum[0][k] + dsum[1][k] + dsum[2][k] + dsum[3][k];
                __hip_atomic_store(gsum + g * 4 + k, v, __ATOMIC_RELAXED,
                                   __HIP_MEMORY_SCOPE_AGENT);
            }
            asm volatile("s_waitcnt vmcnt(0)" ::: "memory");
            int vg = __hip_atomic_fetch_add(ctr + C_TGLOB, 1,
                                            __ATOMIC_RELAXED, __HIP_MEMORY_SCOPE_AGENT);
            flag = (vg == NGRP - 1);
        }
    }
    __syncthreads();
    if (!flag) return;

    // global finisher: sum 32 partials, solve 2x2, residual over targets
    if (warp == 0) {
        double s1 = 0, s2 = 0, t0 = 0, t1 = 0;
        if (lane < NGRP) {
            s1 = __hip_atomic_load(gsum + lane * 4 + 0, __ATOMIC_RELAXED, __HIP_MEMORY_SCOPE_AGENT);
            s2 = __hip_atomic_load(gsum + lane * 4 + 1, __ATOMIC_RELAXED, __HIP_MEMORY_SCOPE_AGENT);
            t0 = __hip_atomic_load(gsum + lane * 4 + 2, __ATOMIC_RELAXED, __HIP_MEMORY_SCOPE_AGENT);
            t1 = __hip_atomic_load(gsum + lane * 4 + 3, __ATOMIC_RELAXED, __HIP_MEMORY_SCOPE_AGENT);
        }
        for (int o = 32; o; o >>= 1) {
            s1 += __shfl_down(s1, o);
            s2 += __shfl_down(s2, o);
            t0 += __shfl_down(t0, o);
            t1 += __shfl_down(t1, o);
        }
        if (lane == 0) {
            double n = (double)NN;
            double det = n * s2 - s1 * s1;
            wb[0] = (n * t1 - s1 * t0) / det;   // w
            wb[1] = (s2 * t0 - s1 * t1) / det;  // b
        }
    }
    __syncthreads();
    const double w = wb[0];
    const double eb = exp(wb[1]);
    const float wf = (float)w;
    double racc = 0;
    for (int p = tid; p < nl; p += 256) {
        int r = lst[p];
        unsigned long long bits = __hip_atomic_load(ND + r, __ATOMIC_RELAXED,
                                                    __HIP_MEMORY_SCOPE_AGENT);
        float2 nd; __builtin_memcpy(&nd, &bits, 8);
        double Nd = (double)nd.x;
        double Ed = Nd + 0.5 * (double)nd.y;
        double pr = (nd.x > 0.f) ? (double)exp2f(wf * log2f(nd.x)) : 0.0;
        double rv = eb * pr - Ed;
        racc += rv * rv;
    }
    for (int o = 32; o; o >>= 1) racc += __shfl_down(racc, o);
    if (lane == 0) sh[warp] = racc;
    __syncthreads();
    if (tid == 0) out[0] = (float)(sh[0] + sh[1] + sh[2] + sh[3]);
}

extern "C" void kernel_launch(void* const* d_in, const int* in_sizes, int n_in,
                              void* d_out, int out_size, void* d_ws, size_t ws_size,
                              hipStream_t stream) {
    const int*   tri_idx = (const int*)d_in[0];
    const float* tri_w   = (const float*)d_in[1];
    const int*   lst     = (const int*)d_in[2];
    const int m  = in_sizes[1];          // number of edges
    const int nl = in_sizes[2];          // number of targets

    char* base = (char*)d_ws;
    int*            ctr  = (int*)base;
    int*            cnt  = (int*)(base + OFF_CNT);
    unsigned short* entp = (unsigned short*)(base + OFF_ENTP);
    unsigned*       e32  = (unsigned*)(base + OFF_ENTP);
    unsigned long long* ND  = (unsigned long long*)(base + OFF_ND);
    unsigned long long* ND2 = (unsigned long long*)(base + OFF_ND2);
    double*         gsum = (double*)(base + OFF_GSUM);
    float*          out  = (float*)d_out;

    zeroall_kernel<<<(Z4 + 255) / 256, 256, 0, stream>>>((float4*)base);
    scatter_kernel<<<(m + 255) / 256, 256, 0, stream>>>(tri_idx, tri_w, cnt, entp, m);
    probe_kernel<<<D3B, 256, 0, stream>>>(cnt, e32, ND2, 1);   // full P2 x8
    probe_kernel<<<D3B, 256, 0, stream>>>(cnt, e32, ND2, 0);   // no-inner x8
    diag3stats_kernel<<<D3B, 256, 0, stream>>>(cnt, e32, ND, lst, nl, ctr, gsum, out);
}

// Round 17
// 43.119 us; speedup vs baseline: 5.0881x; 5.0881x over previous
//
#include <hip/hip_runtime.h>
#include <math.h>

#define NN   4096
#define NN4  (NN/4)
#define CAP  128      // slots per row; Poisson(64) -> never hit
#define RPB  2        // rows per block
#define D3B  (NN/RPB) // 2048 blocks = 8/CU x 256 CU -> fully resident
#define NGRP (D3B/64) // 32 tail groups of 64 blocks
#define GPAD 32       // ints per counter line (128 B)
#define CPAD 32       // ints per scatter counter line (R14: private line/counter)

// counter indices (ints from ctr base) -- tail cascade only
#define C_TGRP  0                  // 32 lines
#define C_TGLOB (32 * GPAD)

// ---- workspace layout (bytes from d_ws) ----
// ctr  @ 0       : 33*GPAD i32 (4.2 KB) tail cascade counters
// cnt  @ 4608    : NN*CPAD i32 (512 KB) one counter per 128 B line
// entp @ 528896  : NN*CAP u16 (1 MiB)   packed col<<4|w entries (ZEROED)
// ND   @ 1577472 : NN u64 (32 KB)       packed float2 {N, D3}
// gsum @ 1610240 : NGRP*4 f64 (1 KB)
#define OFF_CNT  4608
#define OFF_ENTP 528896
#define OFF_ND   1577472
#define OFF_GSUM 1610240
#define ZBYTES   OFF_ND            // zero ctr+cnt+entp
#define Z4       (ZBYTES / 16)

// ---------------- bootstrap: zero ctr + cnt + entp ----------------
// Zero-filled entp is load-bearing (R10): empty slots decode to (col 0, w 0)
// -> contribute exactly 0 -> no masking in the inner loop.
__global__ __launch_bounds__(256) void zeroall_kernel(float4* __restrict__ z) {
    int t = blockIdx.x * 256 + threadIdx.x;
    if (t < Z4) z[t] = make_float4(0.f, 0.f, 0.f, 0.f);
}

// ---------------- scatter: cached 2 B stores, 16-bit entries ----------------
// A = scatter + A^T - diag(diag): row s gets (d,w), row d gets (s,w) once.
// Entry = col<<4 | min(w,15): tri_w are exact small ints (ones); duplicates
// stay raw, merged later in LDS. Whole table 1 MiB -> L2-resident.
__global__ void scatter_kernel(const int* __restrict__ idx,
                               const float* __restrict__ wgt,
                               int* __restrict__ cnt,
                               unsigned short* __restrict__ entp, int m) {
    int e = blockIdx.x * blockDim.x + threadIdx.x;
    if (e < m) {
        int2 sd = ((const int2*)idx)[e];
        int s = sd.x, d = sd.y;
        unsigned ival = (unsigned)(int)wgt[e];
        if (ival > 15u) ival = 15u;
        int p = atomicAdd(cnt + s * CPAD, 1);     // device RMW, private line
        if (p < CAP) entp[(size_t)s * CAP + p] = (unsigned short)(((unsigned)d << 4) | ival);
        if (s != d) {
            int q = atomicAdd(cnt + d * CPAD, 1);
            if (q < CAP) entp[(size_t)d * CAP + q] = (unsigned short)(((unsigned)s << 4) | ival);
        }
    }
}

// ---------------- diag(A^3)/rowsum + cascade OLS/residual tail --------------
// diag(A^3)_i = sum_{(j,w) in row i} w * sum_{(k,w') in row j} w' * A_ik.
// R17: ALL-INTEGER image and accumulation. R16 probe findings: inner loop is
// FREE; cost was per-row scaffolding -- specifically R13's branchless
// atomicAdd(&lrow[0], 0.0f) for empty slots = ~64 same-address float-CAS
// loops per row (float LDS atomicAdd has no native instr -> CAS; same-address
// retries O(64^2)). Fix: int image (native ds_add_u32) + w>0 guard + all
// global loads hoisted to block start. Int adds exact & associative ->
// deterministic.
__global__ __launch_bounds__(256, 8) void diag3stats_kernel(
        const int* __restrict__ cnt, const unsigned* __restrict__ entp32,
        unsigned long long* __restrict__ ND,
        const int* __restrict__ lst, int nl,
        int* __restrict__ ctr, double* __restrict__ gsum,
        float* __restrict__ out) {
    __shared__ int    lrow[NN];      // 16 KB dense int image of current row
    __shared__ int    lcol[CAP];
    __shared__ int    lval[CAP];
    __shared__ int    redI[8];
    __shared__ int    flag;
    __shared__ double dsum[4][4];
    __shared__ double wb[2];
    __shared__ double sh[4];

    const int tid = threadIdx.x, bid = blockIdx.x;
    const int warp = tid >> 6, lane = tid & 63;
    const int i0 = bid * RPB;

    // ---- hoist ALL global inputs for both rows to block start ----
    int mi_arr[RPB];
    #pragma unroll
    for (int r = 0; r < RPB; ++r) {
        int c = cnt[(i0 + r) * CPAD];
        mi_arr[r] = c > CAP ? CAP : c;
    }
    unsigned q_arr[RPB] = {0u, 0u};
    if (tid < 64) {
        #pragma unroll
        for (int r = 0; r < RPB; ++r)
            q_arr[r] = entp32[(size_t)(i0 + r) * 64 + tid];
    }

    int4* l4 = (int4*)lrow;
    for (int rr = 0; rr < RPB; ++rr) {
        const int i = i0 + rr;
        const int mi = mi_arr[rr];
        for (int k = tid; k < NN4; k += 256) l4[k] = make_int4(0, 0, 0, 0);
        __syncthreads();

        int nsum = 0;
        if (tid < 64) {                         // 64 dwords = all 128 slots
            unsigned q = q_arr[rr];
            unsigned e0 = q & 0xffffu, e1 = q >> 16;
            int c0 = (int)(e0 >> 4), c1 = (int)(e1 >> 4);
            int w0 = (int)(e0 & 15u), w1 = (int)(e1 & 15u);
            lcol[2 * tid]     = c0; lval[2 * tid]     = w0;
            lcol[2 * tid + 1] = c1; lval[2 * tid + 1] = w1;
            if (w0) atomicAdd(&lrow[c0], w0);   // native ds_add_u32, guarded
            if (w1) atomicAdd(&lrow[c1], w1);
            nsum = w0 + w1;
        }
        if (warp == 0) {
            for (int o = 32; o; o >>= 1) nsum += __shfl_down(nsum, o);
            if (lane == 0) redI[0] = nsum;
        }
        __syncthreads();

        // inner: one dword/lane = whole 128-slot neighbor row; 4 in flight/wave
        int acc = 0;
        for (int t = warp; t < mi; t += 16) {
            const int t1 = t + 4, t2 = t + 8, t3 = t + 12;
            const bool b1 = t1 < mi, b2 = t2 < mi, b3 = t3 < mi;
            int c0 = lcol[t];
            int c1 = b1 ? lcol[t1] : 0;
            int c2 = b2 ? lcol[t2] : 0;
            int c3 = b3 ? lcol[t3] : 0;
            int a0 = lval[t];
            int a1 = b1 ? lval[t1] : 0;
            int a2 = b2 ? lval[t2] : 0;
            int a3 = b3 ? lval[t3] : 0;
            unsigned q0 = entp32[(size_t)c0 * 64 + lane];   // 4 indep 256 B loads
            unsigned q1 = entp32[(size_t)c1 * 64 + lane];
            unsigned q2 = entp32[(size_t)c2 * 64 + lane];
            unsigned q3 = entp32[(size_t)c3 * 64 + lane];
            int d0 = (int)(q0 & 15u) * lrow[(q0 >> 4) & 4095u]
                   + (int)((q0 >> 16) & 15u) * lrow[q0 >> 20];
            int d1 = (int)(q1 & 15u) * lrow[(q1 >> 4) & 4095u]
                   + (int)((q1 >> 16) & 15u) * lrow[q1 >> 20];
            int d2 = (int)(q2 & 15u) * lrow[(q2 >> 4) & 4095u]
                   + (int)((q2 >> 16) & 15u) * lrow[q2 >> 20];
            int d3 = (int)(q3 & 15u) * lrow[(q3 >> 4) & 4095u]
                   + (int)((q3 >> 16) & 15u) * lrow[q3 >> 20];
            acc += a0 * d0 + a1 * d1 + a2 * d2 + a3 * d3;
        }
        for (int o = 32; o; o >>= 1) acc += __shfl_down(acc, o);
        if (lane == 0) redI[4 + warp] = acc;
        __syncthreads();

        if (tid == 0) {
            float2 nd = make_float2((float)redI[0],
                                    (float)(redI[4] + redI[5] + redI[6] + redI[7]));
            unsigned long long bits;
            __builtin_memcpy(&bits, &nd, 8);
            __hip_atomic_store(ND + i, bits, __ATOMIC_RELAXED, __HIP_MEMORY_SCOPE_AGENT);
        }
        __syncthreads();   // lrow/redI reuse across rows
    }

    // ---- cascade tail (non-blocking; only finishers continue) --------------
    if (tid == 0) {
        asm volatile("s_waitcnt vmcnt(0)" ::: "memory");  // drain ND stores
        int v = __hip_atomic_fetch_add(ctr + C_TGRP + (bid >> 6) * GPAD, 1,
                                       __ATOMIC_RELAXED, __HIP_MEMORY_SCOPE_AGENT);
        flag = (v == 63);
    }
    __syncthreads();
    if (!flag) return;

    // group finisher: 64 blocks x 2 rows = 128 rows -> fp64 OLS partials
    const int g = bid >> 6;
    {
        double p1 = 0, p2 = 0, p3 = 0, p4 = 0;
        if (tid < 128) {
            unsigned long long bits = __hip_atomic_load(ND + (g * 128 + tid),
                                                        __ATOMIC_RELAXED, __HIP_MEMORY_SCOPE_AGENT);
            float2 nd; __builtin_memcpy(&nd, &bits, 8);
            double Nd = (double)nd.x;
            double Ed = Nd + 0.5 * (double)nd.y;
            double ln = (double)logf((float)(Nd + 1e-20));
            double le = (double)logf((float)(Ed + 1e-20));
            p1 = ln; p2 = ln * ln; p3 = le; p4 = ln * le;
        }
        for (int o = 32; o; o >>= 1) {
            p1 += __shfl_down(p1, o);
            p2 += __shfl_down(p2, o);
            p3 += __shfl_down(p3, o);
            p4 += __shfl_down(p4, o);
        }
        if (lane == 0) {
            dsum[warp][0] = p1; dsum[warp][1] = p2;
            dsum[warp][2] = p3; dsum[warp][3] = p4;
        }
        __syncthreads();
        if (tid == 0) {
            for (int k = 0; k < 4; ++k) {
                double v = dsum[0][k] + dsum[1][k] + dsum[2][k] + dsum[3][k];
                __hip_atomic_store(gsum + g * 4 + k, v, __ATOMIC_RELAXED,
                                   __HIP_MEMORY_SCOPE_AGENT);
            }
            asm volatile("s_waitcnt vmcnt(0)" ::: "memory");
            int vg = __hip_atomic_fetch_add(ctr + C_TGLOB, 1,
                                            __ATOMIC_RELAXED, __HIP_MEMORY_SCOPE_AGENT);
            flag = (vg == NGRP - 1);
        }
    }
    __syncthreads();
    if (!flag) return;

    // global finisher: sum 32 partials, solve 2x2, residual over targets
    if (warp == 0) {
        double s1 = 0, s2 = 0, t0 = 0, t1 = 0;
        if (lane < NGRP) {
            s1 = __hip_atomic_load(gsum + lane * 4 + 0, __ATOMIC_RELAXED, __HIP_MEMORY_SCOPE_AGENT);
            s2 = __hip_atomic_load(gsum + lane * 4 + 1, __ATOMIC_RELAXED, __HIP_MEMORY_SCOPE_AGENT);
            t0 = __hip_atomic_load(gsum + lane * 4 + 2, __ATOMIC_RELAXED, __HIP_MEMORY_SCOPE_AGENT);
            t1 = __hip_atomic_load(gsum + lane * 4 + 3, __ATOMIC_RELAXED, __HIP_MEMORY_SCOPE_AGENT);
        }
        for (int o = 32; o; o >>= 1) {
            s1 += __shfl_down(s1, o);
            s2 += __shfl_down(s2, o);
            t0 += __shfl_down(t0, o);
            t1 += __shfl_down(t1, o);
        }
        if (lane == 0) {
            double n = (double)NN;
            double det = n * s2 - s1 * s1;
            wb[0] = (n * t1 - s1 * t0) / det;   // w
            wb[1] = (s2 * t0 - s1 * t1) / det;  // b
        }
    }
    __syncthreads();
    const double w = wb[0];
    const double eb = exp(wb[1]);
    const float wf = (float)w;
    double racc = 0;
    for (int p = tid; p < nl; p += 256) {
        int r = lst[p];
        unsigned long long bits = __hip_atomic_load(ND + r, __ATOMIC_RELAXED,
                                                    __HIP_MEMORY_SCOPE_AGENT);
        float2 nd; __builtin_memcpy(&nd, &bits, 8);
        double Nd = (double)nd.x;
        double Ed = Nd + 0.5 * (double)nd.y;
        double pr = (nd.x > 0.f) ? (double)exp2f(wf * log2f(nd.x)) : 0.0;
        double rv = eb * pr - Ed;
        racc += rv * rv;
    }
    for (int o = 32; o; o >>= 1) racc += __shfl_down(racc, o);
    if (lane == 0) sh[warp] = racc;
    __syncthreads();
    if (tid == 0) out[0] = (float)(sh[0] + sh[1] + sh[2] + sh[3]);
}

extern "C" void kernel_launch(void* const* d_in, const int* in_sizes, int n_in,
                              void* d_out, int out_size, void* d_ws, size_t ws_size,
                              hipStream_t stream) {
    const int*   tri_idx = (const int*)d_in[0];
    const float* tri_w   = (const float*)d_in[1];
    const int*   lst     = (const int*)d_in[2];
    const int m  = in_sizes[1];          // number of edges
    const int nl = in_sizes[2];          // number of targets

    char* base = (char*)d_ws;
    int*            ctr  = (int*)base;
    int*            cnt  = (int*)(base + OFF_CNT);
    unsigned short* entp = (unsigned short*)(base + OFF_ENTP);
    unsigned*       e32  = (unsigned*)(base + OFF_ENTP);
    unsigned long long* ND = (unsigned long long*)(base + OFF_ND);
    double*         gsum = (double*)(base + OFF_GSUM);
    float*          out  = (float*)d_out;

    zeroall_kernel<<<(Z4 + 255) / 256, 256, 0, stream>>>((float4*)base);
    scatter_kernel<<<(m + 255) / 256, 256, 0, stream>>>(tri_idx, tri_w, cnt, entp, m);
    diag3stats_kernel<<<D3B, 256, 0, stream>>>(cnt, e32, ND, lst, nl, ctr, gsum, out);
}